// Round 2
// baseline (355.204 us; speedup 1.0000x reference)
//
#include <hip/hip_runtime.h>

#define ST 512            // sort block threads (8 waves)
#define PT 20             // edges per sort thread (EPB 10240)
#define EPB (ST * PT)     // 10240 edges per sort block
#define CSHIFT 10         // bucket = col >> 10 (width 1024)
#define CMASK 1023u
#define CW 1024           // bucket width == gather-kernel threads
#define NCMAX 255         // max buckets (wave-scan handles NC+1 <= 256 entries)
#define CAP 24576         // slots/bucket (mean 20408, sigma ~143 -> 29 sigma slack)

// ==================== LDS-staged counting sort + fused global deg count ====================
// pack1 = (row << 10) | (col & 1023)   [requires N < 2^22]
// bucket b owns pack1[b*CAP .. b*CAP+gcur[b]) after k_sortk (gcur now a COUNT, zero-init).
// deg[] counted with fire-and-forget global atomics overlapped under sort phases.

__global__ __launch_bounds__(ST) void k_sortk(const int* __restrict__ row,
                                              const int* __restrict__ col,
                                              unsigned* __restrict__ gcur,
                                              unsigned* __restrict__ deg,
                                              unsigned* __restrict__ pack1,
                                              int E, int NC) {
    __shared__ unsigned loff[NCMAX + 2];   // hist -> offsets (inclusive scan)
    __shared__ unsigned gbase[NCMAX + 1];  // per-bucket in-bucket reservation offset
    __shared__ unsigned cur[NCMAX + 1];    // staging placement cursors
    __shared__ unsigned staging[EPB];      // 40 KB packed edges, bucket-grouped

    const int t = threadIdx.x;
    for (int i = t; i <= NC; i += ST) loff[i] = 0;
    __syncthreads();

    const int base = blockIdx.x * EPB;
    int c[PT];

    // ---- load col (kept in registers) ----
#pragma unroll
    for (int k = 0; k < PT / 4; ++k) {
        int e = base + (k * ST + t) * 4;
        int4 cc;
        if (e + 3 < E) {
            cc = *reinterpret_cast<const int4*>(col + e);
        } else {
            cc.x = (e     < E) ? col[e]     : -1;
            cc.y = (e + 1 < E) ? col[e + 1] : -1;
            cc.z = (e + 2 < E) ? col[e + 2] : -1;
            cc.w = (e + 3 < E) ? col[e + 3] : -1;
        }
        c[4 * k] = cc.x; c[4 * k + 1] = cc.y; c[4 * k + 2] = cc.z; c[4 * k + 3] = cc.w;
    }

    // ---- fire-and-forget global degree count (drains under the rest of the kernel) ----
#pragma unroll
    for (int k = 0; k < PT; ++k)
        if (c[k] >= 0) atomicAdd(&deg[c[k]], 1u);

    // ---- LDS histogram into loff[b+1] ----
#pragma unroll
    for (int k = 0; k < PT; ++k)
        if (c[k] >= 0) atomicAdd(&loff[((unsigned)c[k] >> CSHIFT) + 1], 1u);
    __syncthreads();

    // ---- wave-0 shuffle scan of loff[0..NC] ----
    if (t < 64) {
        unsigned v[4];
        unsigned ls = 0;
#pragma unroll
        for (int k = 0; k < 4; ++k) {
            int idx = t * 4 + k;
            v[k] = (idx <= NC) ? loff[idx] : 0;
            ls += v[k];
        }
        unsigned sc = ls;
#pragma unroll
        for (int d = 1; d < 64; d <<= 1) {
            unsigned n = __shfl_up(sc, d, 64);
            if (t >= d) sc += n;
        }
        unsigned run = sc - ls;   // exclusive offset for this lane's 4 entries
#pragma unroll
        for (int k = 0; k < 4; ++k) {
            int idx = t * 4 + k;
            run += v[k];
            if (idx <= NC) loff[idx] = run;   // inclusive scan result
        }
    }
    __syncthreads();

    // ---- per-bucket contiguous reservation (gcur = count within bucket, zero-init) ----
    if (t < NC) {
        unsigned cb = loff[t + 1] - loff[t];
        gbase[t] = atomicAdd(&gcur[t], cb);
        cur[t] = loff[t];
    }
    __syncthreads();

    // ---- place packed edges into LDS staging (bucket-grouped) ----
#pragma unroll
    for (int k = 0; k < PT / 4; ++k) {
        int e = base + (k * ST + t) * 4;
        int4 rr = make_int4(0, 0, 0, 0);
        if (e + 3 < E) {
            rr = *reinterpret_cast<const int4*>(row + e);
        } else {
            rr.x = (e     < E) ? row[e]     : 0;
            rr.y = (e + 1 < E) ? row[e + 1] : 0;
            rr.z = (e + 2 < E) ? row[e + 2] : 0;
            rr.w = (e + 3 < E) ? row[e + 3] : 0;
        }
        int rl[4] = {rr.x, rr.y, rr.z, rr.w};
#pragma unroll
        for (int j = 0; j < 4; ++j) {
            int cc = c[4 * k + j];
            if (cc >= 0) {
                unsigned b = (unsigned)cc >> CSHIFT;
                unsigned p = atomicAdd(&cur[b], 1u);
                staging[p] = ((unsigned)rl[j] << CSHIFT) | ((unsigned)cc & CMASK);
            }
        }
    }
    __syncthreads();

    // ---- coalesced copy-out: one wave per bucket ----
    const int wave = t >> 6;
    const int lane = t & 63;
    for (int b = wave; b < NC; b += ST / 64) {
        unsigned lo = loff[b];
        unsigned hi = loff[b + 1];
        unsigned gb = gbase[b];
        for (unsigned i = lo + lane; i < hi; i += 64) {
            unsigned off = gb + (i - lo);
            if (off < CAP)                      // 29-sigma overflow guard
                pack1[(unsigned)b * CAP + off] = staging[i];
        }
    }
}

// ==================== node-wise dinv/xs (replaces pack1-reading k_degk) ====================

__global__ __launch_bounds__(256) void k_nodek(const unsigned* __restrict__ deg,
                                               const float* __restrict__ x,
                                               float* __restrict__ dinv,
                                               float* __restrict__ xs, int N) {
    int i = blockIdx.x * blockDim.x + threadIdx.x;
    int v = i * 4;
    if (v + 3 < N) {
        uint4 d = *reinterpret_cast<const uint4*>(deg + v);
        float4 xx = *reinterpret_cast<const float4*>(x + v);
        float4 di, xv;
        di.x = rsqrtf((float)d.x + 1.0f); xv.x = di.x * xx.x;
        di.y = rsqrtf((float)d.y + 1.0f); xv.y = di.y * xx.y;
        di.z = rsqrtf((float)d.z + 1.0f); xv.z = di.z * xx.z;
        di.w = rsqrtf((float)d.w + 1.0f); xv.w = di.w * xx.w;
        *reinterpret_cast<float4*>(dinv + v) = di;
        *reinterpret_cast<float4*>(xs + v) = xv;
    } else {
        for (; v < N; ++v) {
            float di = rsqrtf((float)deg[v] + 1.0f);
            dinv[v] = di;
            xs[v] = di * x[v];
        }
    }
}

// ==================== per-bucket gather kernels (1024 threads, 1 node/thread) ====================

__global__ __launch_bounds__(CW) void k_l1k(const unsigned* __restrict__ pack1,
                                            const unsigned* __restrict__ gcur,
                                            const float* __restrict__ xs,
                                            const float* __restrict__ dinv,
                                            const float* __restrict__ W1,
                                            const float* __restrict__ b1,
                                            const float* __restrict__ W2,
                                            float* __restrict__ gs, int N) {
    __shared__ float acc[CW];
    const int b = blockIdx.x;
    const int t = threadIdx.x;
    acc[t] = 0.0f;
    __syncthreads();
    unsigned cnt = gcur[b];
    if (cnt > CAP) cnt = CAP;
    unsigned s0 = (unsigned)b * CAP;
    unsigned s1 = s0 + cnt;
    unsigned n4 = cnt >> 2;
    const uint4* pk = reinterpret_cast<const uint4*>(pack1 + s0);
    unsigned i = t;
    for (; i + CW < n4; i += 2 * CW) {
        uint4 pa = pk[i];
        uint4 pb = pk[i + CW];
        float a0 = xs[pa.x >> CSHIFT];
        float a1 = xs[pa.y >> CSHIFT];
        float a2 = xs[pa.z >> CSHIFT];
        float a3 = xs[pa.w >> CSHIFT];
        float c0 = xs[pb.x >> CSHIFT];
        float c1 = xs[pb.y >> CSHIFT];
        float c2 = xs[pb.z >> CSHIFT];
        float c3 = xs[pb.w >> CSHIFT];
        atomicAdd(&acc[pa.x & CMASK], a0);
        atomicAdd(&acc[pa.y & CMASK], a1);
        atomicAdd(&acc[pa.z & CMASK], a2);
        atomicAdd(&acc[pa.w & CMASK], a3);
        atomicAdd(&acc[pb.x & CMASK], c0);
        atomicAdd(&acc[pb.y & CMASK], c1);
        atomicAdd(&acc[pb.z & CMASK], c2);
        atomicAdd(&acc[pb.w & CMASK], c3);
    }
    if (i < n4) {
        uint4 pa = pk[i];
        float a0 = xs[pa.x >> CSHIFT];
        float a1 = xs[pa.y >> CSHIFT];
        float a2 = xs[pa.z >> CSHIFT];
        float a3 = xs[pa.w >> CSHIFT];
        atomicAdd(&acc[pa.x & CMASK], a0);
        atomicAdd(&acc[pa.y & CMASK], a1);
        atomicAdd(&acc[pa.z & CMASK], a2);
        atomicAdd(&acc[pa.w & CMASK], a3);
    }
    unsigned j = s0 + (n4 << 2) + t;
    if (j < s1) {
        unsigned p = pack1[j];
        atomicAdd(&acc[p & CMASK], xs[p >> CSHIFT]);
    }
    __syncthreads();
    int v = (b << CSHIFT) + t;
    if (v < N) {
        float di = dinv[v];
        float tt = di * (acc[t] + xs[v]);  // + self-loop
        float g = 0.0f;
#pragma unroll
        for (int jj = 0; jj < 16; ++jj) {
            float y = fmaxf(fmaf(W1[jj], tt, b1[jj]), 0.0f);
            g = fmaf(W2[2 * jj] - W2[2 * jj + 1], y, g);
        }
        gs[v] = di * g;
    }
}

__global__ __launch_bounds__(CW) void k_l2k(const unsigned* __restrict__ pack1,
                                            const unsigned* __restrict__ gcur,
                                            const float* __restrict__ gs,
                                            const float* __restrict__ dinv,
                                            const float* __restrict__ b2,
                                            float* __restrict__ out, int N) {
    __shared__ float acc[CW];
    const int b = blockIdx.x;
    const int t = threadIdx.x;
    acc[t] = 0.0f;
    __syncthreads();
    unsigned cnt = gcur[b];
    if (cnt > CAP) cnt = CAP;
    unsigned s0 = (unsigned)b * CAP;
    unsigned s1 = s0 + cnt;
    unsigned n4 = cnt >> 2;
    const uint4* pk = reinterpret_cast<const uint4*>(pack1 + s0);
    unsigned i = t;
    for (; i + CW < n4; i += 2 * CW) {
        uint4 pa = pk[i];
        uint4 pb = pk[i + CW];
        float a0 = gs[pa.x >> CSHIFT];
        float a1 = gs[pa.y >> CSHIFT];
        float a2 = gs[pa.z >> CSHIFT];
        float a3 = gs[pa.w >> CSHIFT];
        float c0 = gs[pb.x >> CSHIFT];
        float c1 = gs[pb.y >> CSHIFT];
        float c2 = gs[pb.z >> CSHIFT];
        float c3 = gs[pb.w >> CSHIFT];
        atomicAdd(&acc[pa.x & CMASK], a0);
        atomicAdd(&acc[pa.y & CMASK], a1);
        atomicAdd(&acc[pa.z & CMASK], a2);
        atomicAdd(&acc[pa.w & CMASK], a3);
        atomicAdd(&acc[pb.x & CMASK], c0);
        atomicAdd(&acc[pb.y & CMASK], c1);
        atomicAdd(&acc[pb.z & CMASK], c2);
        atomicAdd(&acc[pb.w & CMASK], c3);
    }
    if (i < n4) {
        uint4 pa = pk[i];
        float a0 = gs[pa.x >> CSHIFT];
        float a1 = gs[pa.y >> CSHIFT];
        float a2 = gs[pa.z >> CSHIFT];
        float a3 = gs[pa.w >> CSHIFT];
        atomicAdd(&acc[pa.x & CMASK], a0);
        atomicAdd(&acc[pa.y & CMASK], a1);
        atomicAdd(&acc[pa.z & CMASK], a2);
        atomicAdd(&acc[pa.w & CMASK], a3);
    }
    unsigned j = s0 + (n4 << 2) + t;
    if (j < s1) {
        unsigned p = pack1[j];
        atomicAdd(&acc[p & CMASK], gs[p >> CSHIFT]);
    }
    __syncthreads();
    int v = (b << CSHIFT) + t;
    if (v < N) {
        float diff = dinv[v] * (acc[t] + gs[v]) + (b2[0] - b2[1]);
        float p0 = 1.0f / (1.0f + __expf(-diff));
        float2 o;
        o.x = p0;
        o.y = 1.0f - p0;
        reinterpret_cast<float2*>(out)[v] = o;
    }
}

// ==================== generic fallback (R2 atomic path, any sizes) ====================
__global__ void k_zero_f(float* __restrict__ p, int n) {
    int i = blockIdx.x * blockDim.x + threadIdx.x;
    int v = i * 4;
    if (v + 3 < n) {
        reinterpret_cast<float4*>(p + v)[0] = make_float4(0.f, 0.f, 0.f, 0.f);
    } else {
        for (; v < n; ++v) p[v] = 0.0f;
    }
}
__global__ void k_deg_f(const int* __restrict__ col, float* __restrict__ deg, int E) {
    int i = blockIdx.x * blockDim.x + threadIdx.x;
    int e = i * 4;
    if (e + 3 < E) {
        int4 c = reinterpret_cast<const int4*>(col + e)[0];
        atomicAdd(deg + c.x, 1.0f); atomicAdd(deg + c.y, 1.0f);
        atomicAdd(deg + c.z, 1.0f); atomicAdd(deg + c.w, 1.0f);
    } else {
        for (; e < E; ++e) atomicAdd(deg + col[e], 1.0f);
    }
}
__global__ void k_node1_f(const float* __restrict__ x, float* __restrict__ degdinv,
                          float* __restrict__ xs, int N) {
    int v = blockIdx.x * blockDim.x + threadIdx.x;
    if (v < N) {
        float dinv = rsqrtf(degdinv[v] + 1.0f);
        degdinv[v] = dinv;
        xs[v] = dinv * x[v];
    }
}
__global__ void k_scat_f(const int* __restrict__ row, const int* __restrict__ col,
                         const float* __restrict__ src, float* __restrict__ acc, int E) {
    int i = blockIdx.x * blockDim.x + threadIdx.x;
    int e = i * 4;
    if (e + 3 < E) {
        int4 r = reinterpret_cast<const int4*>(row + e)[0];
        int4 c = reinterpret_cast<const int4*>(col + e)[0];
        float s0 = src[r.x], s1 = src[r.y], s2 = src[r.z], s3 = src[r.w];
        atomicAdd(acc + c.x, s0); atomicAdd(acc + c.y, s1);
        atomicAdd(acc + c.z, s2); atomicAdd(acc + c.w, s3);
    } else {
        for (; e < E; ++e) atomicAdd(acc + col[e], src[row[e]]);
    }
}
__global__ void k_mlp_f(const float* __restrict__ W1, const float* __restrict__ b1,
                        const float* __restrict__ W2, const float* __restrict__ dinv,
                        float* __restrict__ acc, float* __restrict__ xsgs, int N) {
    int v = blockIdx.x * blockDim.x + threadIdx.x;
    if (v < N) {
        float di = dinv[v];
        float t = di * (acc[v] + xsgs[v]);
        float g = 0.0f;
#pragma unroll
        for (int j = 0; j < 16; ++j) {
            float y = fmaxf(fmaf(W1[j], t, b1[j]), 0.0f);
            g = fmaf(W2[2 * j] - W2[2 * j + 1], y, g);
        }
        xsgs[v] = di * g;
        acc[v] = 0.0f;
    }
}
__global__ void k_out_f(const float* __restrict__ b2, const float* __restrict__ dinv,
                        const float* __restrict__ acc, const float* __restrict__ gs,
                        float* __restrict__ out, int N) {
    int v = blockIdx.x * blockDim.x + threadIdx.x;
    if (v < N) {
        float diff = dinv[v] * (acc[v] + gs[v]) + (b2[0] - b2[1]);
        float p0 = 1.0f / (1.0f + __expf(-diff));
        float2 o; o.x = p0; o.y = 1.0f - p0;
        reinterpret_cast<float2*>(out)[v] = o;
    }
}

extern "C" void kernel_launch(void* const* d_in, const int* in_sizes, int n_in,
                              void* d_out, int out_size, void* d_ws, size_t ws_size,
                              hipStream_t stream) {
    const float* x  = (const float*)d_in[0];
    const int* edge = (const int*)d_in[1];   // int64 in reference -> int32 in harness
    const float* W1 = (const float*)d_in[2];
    const float* b1 = (const float*)d_in[3];
    const float* W2 = (const float*)d_in[4];
    const float* b2 = (const float*)d_in[5];
    float* out = (float*)d_out;

    const int N = in_sizes[0];
    const int E = in_sizes[1] / 2;
    const int* row = edge;       // sources
    const int* col = edge + E;   // targets

    const int NC  = (N + CW - 1) >> CSHIFT;            // buckets (245)
    const int NBS = (E + EPB - 1) / EPB;               // sort blocks (489, all co-resident)

    // Capacity check: mean + 8 sigma must fit CAP.
    const double mean = (double)E / NC;
    const double slack = mean + 8.0 * __builtin_sqrt(mean > 1.0 ? mean : 1.0);
    // ws: pack1[NC*CAP] | gcur[NC] | deg[N] (u32) then dinv[N] | xs[N] | gs[N] (floats)
    const size_t need = ((size_t)NC * CAP + NC + (size_t)4 * N) * 4;

    if (NC <= NCMAX && N < (1 << 22) && slack < CAP && ws_size >= need) {
        unsigned* pack1 = (unsigned*)d_ws;
        unsigned* gcur  = pack1 + (size_t)NC * CAP;
        unsigned* deg   = gcur + NC;
        float* dinv     = (float*)(deg + N);
        float* xs       = dinv + N;
        float* gs       = xs + N;

        const int nb4 = ((N + 3) / 4 + 255) / 256;

        // Split launches: kernel boundary is the cheap device-wide sync on
        // gfx950 (cooperative grid.sync -> per-block device-scope L2 flushes
        // across non-coherent XCDs -> 3.5x regression, R8).
        hipMemsetAsync(gcur, 0, (size_t)(NC + N) * sizeof(unsigned), stream);
        k_sortk<<<NBS, ST, 0, stream>>>(row, col, gcur, deg, pack1, E, NC);
        k_nodek<<<nb4, 256, 0, stream>>>(deg, x, dinv, xs, N);
        k_l1k  <<<NC, CW, 0, stream>>>(pack1, gcur, xs, dinv, W1, b1, W2, gs, N);
        k_l2k  <<<NC, CW, 0, stream>>>(pack1, gcur, gs, dinv, b2, out, N);
    } else {
        // generic fallback: R2 atomic-scatter path
        float* w0 = (float*)d_ws;
        float* w1 = w0 + N;
        float* w2 = w1 + N;
        const int nb = (N + 255) / 256;
        const int eb = ((E + 3) / 4 + 255) / 256;
        const int zb = ((2 * N + 3) / 4 + 255) / 256;
        k_zero_f <<<zb, 256, 0, stream>>>(w0, 2 * N);
        k_deg_f  <<<eb, 256, 0, stream>>>(col, w0, E);
        k_node1_f<<<nb, 256, 0, stream>>>(x, w0, w2, N);
        k_scat_f <<<eb, 256, 0, stream>>>(row, col, w2, w1, E);
        k_mlp_f  <<<nb, 256, 0, stream>>>(W1, b1, W2, w0, w1, w2, N);
        k_scat_f <<<eb, 256, 0, stream>>>(row, col, w2, w1, E);
        k_out_f  <<<nb, 256, 0, stream>>>(b2, w0, w1, w2, out, N);
    }
}

// Round 3
// 275.087 us; speedup vs baseline: 1.2912x; 1.2912x over previous
//
#include <hip/hip_runtime.h>

#define ST 512            // sort block threads (8 waves)
#define PT 20             // edges per sort thread (EPB 10240)
#define EPB (ST * PT)     // 10240 edges per sort block
#define CSHIFT 10         // bucket = col >> 10 (width 1024)
#define CMASK 1023u
#define CW 1024           // bucket width == gather-kernel threads
#define NCMAX 255         // max buckets
#define NS 8              // row slices per bucket
#define SSHIFT 15         // slice = row >> 15 (32768 nodes/slice)
#define SMASK 32767u
#define SLICE 32768       // nodes per slice (128 KB fp32 in LDS)
#define SUBCAP 3072       // slots per (bucket,slice): mean 2551, sigma 50 -> +10 sigma
#define CAP (NS * SUBCAP) // 24576 slots/bucket (same pack1 footprint as before)

// ==================== LDS-staged counting sort, slice-ordered output ====================
// pack1 = (row << 10) | (col & 1023)   [requires N <= NS*SLICE = 262144]
// sub-bucket sb = b*NS + s owns pack1[sb*SUBCAP .. gcur[sb]) after k_sortk
// (gcur[sb] init to sb*SUBCAP, advanced by copy-out ballot atomics).

__global__ void k_init(unsigned* __restrict__ gcur, int NSB) {
    for (int i = threadIdx.x; i < NSB; i += blockDim.x)
        gcur[i] = (unsigned)i * SUBCAP;
}

__global__ __launch_bounds__(ST) void k_sortk(const int* __restrict__ row,
                                              const int* __restrict__ col,
                                              unsigned* __restrict__ gcur,
                                              unsigned* __restrict__ pack1,
                                              int E, int NC) {
    __shared__ unsigned loff[NCMAX + 2];   // hist -> offsets (inclusive scan)
    __shared__ unsigned cur[NCMAX + 1];    // staging placement cursors
    __shared__ unsigned staging[EPB];      // 40 KB packed edges, bucket-grouped

    const int t = threadIdx.x;
    for (int i = t; i <= NC; i += ST) loff[i] = 0;
    __syncthreads();

    const int base = blockIdx.x * EPB;
    int c[PT];

    // ---- load col (kept in registers), histogram into loff[b+1] ----
#pragma unroll
    for (int k = 0; k < PT / 4; ++k) {
        int e = base + (k * ST + t) * 4;
        int4 cc;
        if (e + 3 < E) {
            cc = *reinterpret_cast<const int4*>(col + e);
        } else {
            cc.x = (e     < E) ? col[e]     : -1;
            cc.y = (e + 1 < E) ? col[e + 1] : -1;
            cc.z = (e + 2 < E) ? col[e + 2] : -1;
            cc.w = (e + 3 < E) ? col[e + 3] : -1;
        }
        c[4 * k] = cc.x; c[4 * k + 1] = cc.y; c[4 * k + 2] = cc.z; c[4 * k + 3] = cc.w;
    }
#pragma unroll
    for (int k = 0; k < PT; ++k)
        if (c[k] >= 0) atomicAdd(&loff[((unsigned)c[k] >> CSHIFT) + 1], 1u);
    __syncthreads();

    // ---- wave-0 shuffle scan of loff[0..NC] ----
    if (t < 64) {
        unsigned v[4];
        unsigned ls = 0;
#pragma unroll
        for (int k = 0; k < 4; ++k) {
            int idx = t * 4 + k;
            v[k] = (idx <= NC) ? loff[idx] : 0;
            ls += v[k];
        }
        unsigned sc = ls;
#pragma unroll
        for (int d = 1; d < 64; d <<= 1) {
            unsigned n = __shfl_up(sc, d, 64);
            if (t >= d) sc += n;
        }
        unsigned run = sc - ls;   // exclusive offset for this lane's 4 entries
#pragma unroll
        for (int k = 0; k < 4; ++k) {
            int idx = t * 4 + k;
            run += v[k];
            if (idx <= NC) loff[idx] = run;   // inclusive scan result
        }
    }
    __syncthreads();

    if (t < NC) cur[t] = loff[t];
    __syncthreads();

    // ---- place packed edges into LDS staging (bucket-grouped) ----
#pragma unroll
    for (int k = 0; k < PT / 4; ++k) {
        int e = base + (k * ST + t) * 4;
        int4 rr = make_int4(0, 0, 0, 0);
        if (e + 3 < E) {
            rr = *reinterpret_cast<const int4*>(row + e);
        } else {
            rr.x = (e     < E) ? row[e]     : 0;
            rr.y = (e + 1 < E) ? row[e + 1] : 0;
            rr.z = (e + 2 < E) ? row[e + 2] : 0;
            rr.w = (e + 3 < E) ? row[e + 3] : 0;
        }
        int rl[4] = {rr.x, rr.y, rr.z, rr.w};
#pragma unroll
        for (int j = 0; j < 4; ++j) {
            int cc = c[4 * k + j];
            if (cc >= 0) {
                unsigned b = (unsigned)cc >> CSHIFT;
                unsigned p = atomicAdd(&cur[b], 1u);
                staging[p] = ((unsigned)rl[j] << CSHIFT) | ((unsigned)cc & CMASK);
            }
        }
    }
    __syncthreads();

    // ---- copy-out: one wave per bucket, slice-ordered via ballot aggregation ----
    // 8 ballots classify the wave's <=64 edges by row-slice; lanes 0..7 issue the
    // 8 per-slice global reservations CONCURRENTLY (one atomic latency per chunk).
    const int wave = t >> 6;
    const int lane = t & 63;
    const unsigned long long lanemask_lt = (lane == 0) ? 0ull : ((~0ull) >> (64 - lane));
    for (int b = wave; b < NC; b += ST / 64) {
        unsigned lo = loff[b];
        unsigned hi = loff[b + 1];
        for (unsigned i0 = lo; i0 < hi; i0 += 64) {
            unsigned i = i0 + lane;
            bool valid = i < hi;
            unsigned p = valid ? staging[i] : 0u;
            unsigned sl = p >> (CSHIFT + SSHIFT);   // row slice, 3 bits
            unsigned long long mymask = 0;
            unsigned cnt8 = 0;
#pragma unroll
            for (int s = 0; s < NS; ++s) {
                unsigned long long m = __ballot(valid && sl == (unsigned)s);
                if (valid && sl == (unsigned)s) mymask = m;
                if (lane == s) cnt8 = (unsigned)__popcll(m);
            }
            unsigned rbase = 0;
            if (lane < NS && cnt8)
                rbase = atomicAdd(&gcur[b * NS + lane], cnt8);
            unsigned mybase = __shfl(rbase, (int)sl, 64);
            if (valid) {
                unsigned rank = (unsigned)__popcll(mymask & lanemask_lt);
                unsigned pos = mybase + rank;
                if (pos < ((unsigned)b * NS + sl + 1u) * (unsigned)SUBCAP)  // overflow guard
                    pack1[pos] = p;
            }
        }
    }
}

// ==================== per-bucket degree + dinv/xs (sub-segment scan) ====================

__global__ __launch_bounds__(CW) void k_degk(const unsigned* __restrict__ pack1,
                                             const unsigned* __restrict__ gcur,
                                             const float* __restrict__ x,
                                             float* __restrict__ dinv, float* __restrict__ xs,
                                             int N) {
    __shared__ unsigned dcnt[CW];
    const int b = blockIdx.x;
    const int t = threadIdx.x;
    dcnt[t] = 0;
    __syncthreads();
    for (int s = 0; s < NS; ++s) {
        unsigned sb = (unsigned)b * NS + s;
        unsigned sbase = sb * SUBCAP;
        unsigned cnt = min(gcur[sb] - sbase, (unsigned)SUBCAP);
        for (unsigned i = t; i < cnt; i += CW)
            atomicAdd(&dcnt[pack1[sbase + i] & CMASK], 1u);
    }
    __syncthreads();
    int v = (b << CSHIFT) + t;
    if (v < N) {
        float di = rsqrtf((float)dcnt[t] + 1.0f);
        dinv[v] = di;
        xs[v] = di * x[v];
    }
}

// ==================== per-bucket gather kernels: slice-staged LDS gather ====================
// dynamic LDS: 128 KB xs/gs slice buffer; gathers become LDS reads (no L1 misses).

__global__ __launch_bounds__(CW) void k_l1k(const unsigned* __restrict__ pack1,
                                            const unsigned* __restrict__ gcur,
                                            const float* __restrict__ xs,
                                            const float* __restrict__ dinv,
                                            const float* __restrict__ W1,
                                            const float* __restrict__ b1,
                                            const float* __restrict__ W2,
                                            float* __restrict__ gs, int N) {
    extern __shared__ float sbuf[];        // SLICE floats = 128 KB
    __shared__ float acc[CW];
    const int b = blockIdx.x;
    const int t = threadIdx.x;
    acc[t] = 0.0f;
    const int n4 = N >> 2;                 // N multiple-of-4 guaranteed by host guard
    for (int s = 0; s < NS; ++s) {
        const float4* x4 = reinterpret_cast<const float4*>(xs) + s * (SLICE / 4);
        float4* b4 = reinterpret_cast<float4*>(sbuf);
        const int lim = n4 - s * (SLICE / 4);
#pragma unroll
        for (int k = 0; k < SLICE / 4 / CW; ++k) {   // 8 coalesced float4 loads/thread
            int j = k * CW + t;
            b4[j] = (j < lim) ? x4[j] : make_float4(0.f, 0.f, 0.f, 0.f);
        }
        __syncthreads();
        unsigned sb = (unsigned)b * NS + s;
        unsigned sbase = sb * SUBCAP;
        unsigned cnt = min(gcur[sb] - sbase, (unsigned)SUBCAP);
        for (unsigned i = t; i < cnt; i += CW) {
            unsigned p = pack1[sbase + i];
            atomicAdd(&acc[p & CMASK], sbuf[(p >> CSHIFT) & SMASK]);
        }
        __syncthreads();
    }
    int v = (b << CSHIFT) + t;
    if (v < N) {
        float di = dinv[v];
        float tt = di * (acc[t] + xs[v]);  // + self-loop
        float g = 0.0f;
#pragma unroll
        for (int jj = 0; jj < 16; ++jj) {
            float y = fmaxf(fmaf(W1[jj], tt, b1[jj]), 0.0f);
            g = fmaf(W2[2 * jj] - W2[2 * jj + 1], y, g);
        }
        gs[v] = di * g;
    }
}

__global__ __launch_bounds__(CW) void k_l2k(const unsigned* __restrict__ pack1,
                                            const unsigned* __restrict__ gcur,
                                            const float* __restrict__ gs,
                                            const float* __restrict__ dinv,
                                            const float* __restrict__ b2,
                                            float* __restrict__ out, int N) {
    extern __shared__ float sbuf[];
    __shared__ float acc[CW];
    const int b = blockIdx.x;
    const int t = threadIdx.x;
    acc[t] = 0.0f;
    const int n4 = N >> 2;
    for (int s = 0; s < NS; ++s) {
        const float4* g4 = reinterpret_cast<const float4*>(gs) + s * (SLICE / 4);
        float4* b4 = reinterpret_cast<float4*>(sbuf);
        const int lim = n4 - s * (SLICE / 4);
#pragma unroll
        for (int k = 0; k < SLICE / 4 / CW; ++k) {
            int j = k * CW + t;
            b4[j] = (j < lim) ? g4[j] : make_float4(0.f, 0.f, 0.f, 0.f);
        }
        __syncthreads();
        unsigned sb = (unsigned)b * NS + s;
        unsigned sbase = sb * SUBCAP;
        unsigned cnt = min(gcur[sb] - sbase, (unsigned)SUBCAP);
        for (unsigned i = t; i < cnt; i += CW) {
            unsigned p = pack1[sbase + i];
            atomicAdd(&acc[p & CMASK], sbuf[(p >> CSHIFT) & SMASK]);
        }
        __syncthreads();
    }
    int v = (b << CSHIFT) + t;
    if (v < N) {
        float diff = dinv[v] * (acc[t] + gs[v]) + (b2[0] - b2[1]);
        float p0 = 1.0f / (1.0f + __expf(-diff));
        float2 o;
        o.x = p0;
        o.y = 1.0f - p0;
        reinterpret_cast<float2*>(out)[v] = o;
    }
}

// ==================== generic fallback (R2 atomic path, any sizes) ====================
__global__ void k_zero_f(float* __restrict__ p, int n) {
    int i = blockIdx.x * blockDim.x + threadIdx.x;
    int v = i * 4;
    if (v + 3 < n) {
        reinterpret_cast<float4*>(p + v)[0] = make_float4(0.f, 0.f, 0.f, 0.f);
    } else {
        for (; v < n; ++v) p[v] = 0.0f;
    }
}
__global__ void k_deg_f(const int* __restrict__ col, float* __restrict__ deg, int E) {
    int i = blockIdx.x * blockDim.x + threadIdx.x;
    int e = i * 4;
    if (e + 3 < E) {
        int4 c = reinterpret_cast<const int4*>(col + e)[0];
        atomicAdd(deg + c.x, 1.0f); atomicAdd(deg + c.y, 1.0f);
        atomicAdd(deg + c.z, 1.0f); atomicAdd(deg + c.w, 1.0f);
    } else {
        for (; e < E; ++e) atomicAdd(deg + col[e], 1.0f);
    }
}
__global__ void k_node1_f(const float* __restrict__ x, float* __restrict__ degdinv,
                          float* __restrict__ xs, int N) {
    int v = blockIdx.x * blockDim.x + threadIdx.x;
    if (v < N) {
        float dinv = rsqrtf(degdinv[v] + 1.0f);
        degdinv[v] = dinv;
        xs[v] = dinv * x[v];
    }
}
__global__ void k_scat_f(const int* __restrict__ row, const int* __restrict__ col,
                         const float* __restrict__ src, float* __restrict__ acc, int E) {
    int i = blockIdx.x * blockDim.x + threadIdx.x;
    int e = i * 4;
    if (e + 3 < E) {
        int4 r = reinterpret_cast<const int4*>(row + e)[0];
        int4 c = reinterpret_cast<const int4*>(col + e)[0];
        float s0 = src[r.x], s1 = src[r.y], s2 = src[r.z], s3 = src[r.w];
        atomicAdd(acc + c.x, s0); atomicAdd(acc + c.y, s1);
        atomicAdd(acc + c.z, s2); atomicAdd(acc + c.w, s3);
    } else {
        for (; e < E; ++e) atomicAdd(acc + col[e], src[row[e]]);
    }
}
__global__ void k_mlp_f(const float* __restrict__ W1, const float* __restrict__ b1,
                        const float* __restrict__ W2, const float* __restrict__ dinv,
                        float* __restrict__ acc, float* __restrict__ xsgs, int N) {
    int v = blockIdx.x * blockDim.x + threadIdx.x;
    if (v < N) {
        float di = dinv[v];
        float t = di * (acc[v] + xsgs[v]);
        float g = 0.0f;
#pragma unroll
        for (int j = 0; j < 16; ++j) {
            float y = fmaxf(fmaf(W1[j], t, b1[j]), 0.0f);
            g = fmaf(W2[2 * j] - W2[2 * j + 1], y, g);
        }
        xsgs[v] = di * g;
        acc[v] = 0.0f;
    }
}
__global__ void k_out_f(const float* __restrict__ b2, const float* __restrict__ dinv,
                        const float* __restrict__ acc, const float* __restrict__ gs,
                        float* __restrict__ out, int N) {
    int v = blockIdx.x * blockDim.x + threadIdx.x;
    if (v < N) {
        float diff = dinv[v] * (acc[v] + gs[v]) + (b2[0] - b2[1]);
        float p0 = 1.0f / (1.0f + __expf(-diff));
        float2 o; o.x = p0; o.y = 1.0f - p0;
        reinterpret_cast<float2*>(out)[v] = o;
    }
}

extern "C" void kernel_launch(void* const* d_in, const int* in_sizes, int n_in,
                              void* d_out, int out_size, void* d_ws, size_t ws_size,
                              hipStream_t stream) {
    const float* x  = (const float*)d_in[0];
    const int* edge = (const int*)d_in[1];   // int64 in reference -> int32 in harness
    const float* W1 = (const float*)d_in[2];
    const float* b1 = (const float*)d_in[3];
    const float* W2 = (const float*)d_in[4];
    const float* b2 = (const float*)d_in[5];
    float* out = (float*)d_out;

    const int N = in_sizes[0];
    const int E = in_sizes[1] / 2;
    const int* row = edge;       // sources
    const int* col = edge + E;   // targets

    const int NC  = (N + CW - 1) >> CSHIFT;            // buckets (245)
    const int NSB = NC * NS;                           // sub-buckets (1960)
    const int NBS = (E + EPB - 1) / EPB;               // sort blocks (489)

    // Capacity check: per-(bucket,slice) mean + 8 sigma must fit SUBCAP.
    const double mean_sb = (double)E / ((double)NC * NS);
    const double slack = mean_sb + 8.0 * __builtin_sqrt(mean_sb > 1.0 ? mean_sb : 1.0);
    // ws: pack1[NC*CAP] | gcur[NSB] (u32) then dinv[N] | xs[N] | gs[N] (floats)
    const size_t need = ((size_t)NC * CAP + NSB) * 4 + (size_t)3 * N * 4;

    if (NC <= NCMAX && N <= NS * SLICE && (N & 3) == 0 && slack < SUBCAP &&
        ws_size >= need) {
        unsigned* pack1 = (unsigned*)d_ws;
        unsigned* gcur  = pack1 + (size_t)NC * CAP;
        float* dinv     = (float*)(gcur + NSB);
        float* xs       = dinv + N;
        float* gs       = xs + N;

        // dynamic LDS 128 KB > 64 KB default: raise the cap once (host-side, not
        // stream-ordered -> graph-capture safe).
        static bool attr_done = false;
        if (!attr_done) {
            hipFuncSetAttribute((const void*)k_l1k,
                                hipFuncAttributeMaxDynamicSharedMemorySize, SLICE * 4);
            hipFuncSetAttribute((const void*)k_l2k,
                                hipFuncAttributeMaxDynamicSharedMemorySize, SLICE * 4);
            attr_done = true;
        }

        // Split launches: kernel boundary is the cheap device-wide sync on
        // gfx950 (cooperative grid.sync -> 3.5x regression, R8).
        k_init <<<1, 256, 0, stream>>>(gcur, NSB);
        k_sortk<<<NBS, ST, 0, stream>>>(row, col, gcur, pack1, E, NC);
        k_degk <<<NC, CW, 0, stream>>>(pack1, gcur, x, dinv, xs, N);
        k_l1k  <<<NC, CW, SLICE * 4, stream>>>(pack1, gcur, xs, dinv, W1, b1, W2, gs, N);
        k_l2k  <<<NC, CW, SLICE * 4, stream>>>(pack1, gcur, gs, dinv, b2, out, N);
    } else {
        // generic fallback: R2 atomic-scatter path
        float* w0 = (float*)d_ws;
        float* w1 = w0 + N;
        float* w2 = w1 + N;
        const int nb = (N + 255) / 256;
        const int eb = ((E + 3) / 4 + 255) / 256;
        const int zb = ((2 * N + 3) / 4 + 255) / 256;
        k_zero_f <<<zb, 256, 0, stream>>>(w0, 2 * N);
        k_deg_f  <<<eb, 256, 0, stream>>>(col, w0, E);
        k_node1_f<<<nb, 256, 0, stream>>>(x, w0, w2, N);
        k_scat_f <<<eb, 256, 0, stream>>>(row, col, w2, w1, E);
        k_mlp_f  <<<nb, 256, 0, stream>>>(W1, b1, W2, w0, w1, w2, N);
        k_scat_f <<<eb, 256, 0, stream>>>(row, col, w2, w1, E);
        k_out_f  <<<nb, 256, 0, stream>>>(b2, w0, w1, w2, out, N);
    }
}

// Round 4
// 250.001 us; speedup vs baseline: 1.4208x; 1.1003x over previous
//
#include <hip/hip_runtime.h>

#define ST 512            // sort block threads (8 waves)
#define PT 20             // edges per sort thread (EPB 10240)
#define EPB (ST * PT)     // 10240 edges per sort block
#define CSHIFT 10         // bucket = col >> 10 (width 1024)
#define CMASK 1023u
#define CW 1024           // bucket width == gather-kernel threads
#define NCMAX 255         // max buckets/tiles (wave-scan handles <=256 entries)
#define CAP 24576         // slots/bucket (mean 20408, sigma ~143 -> 29 sigma slack)
#define NWAVE (CW / 64)   // 16 waves per gather block

// ==================== stage 1: LDS-staged counting sort by col-bucket ====================
// pack1 = (row << 10) | (col & 1023)   [requires N < 2^22]
// bucket b owns pack1[b*CAP .. b*CAP+gcur[b])  (gcur = per-bucket COUNT, zero-init).

__global__ __launch_bounds__(ST) void k_sortk(const int* __restrict__ row,
                                              const int* __restrict__ col,
                                              unsigned* __restrict__ gcur,
                                              unsigned* __restrict__ pack1,
                                              int E, int NC) {
    __shared__ unsigned loff[NCMAX + 2];   // hist -> offsets (inclusive scan)
    __shared__ unsigned gbase[NCMAX + 1];  // per-bucket in-bucket reservation base
    __shared__ unsigned cur[NCMAX + 1];    // staging placement cursors
    __shared__ unsigned staging[EPB];      // 40 KB packed edges, bucket-grouped

    const int t = threadIdx.x;
    for (int i = t; i <= NC; i += ST) loff[i] = 0;
    __syncthreads();

    const int base = blockIdx.x * EPB;
    int c[PT];

    // ---- load col (kept in registers), histogram into loff[b+1] ----
#pragma unroll
    for (int k = 0; k < PT / 4; ++k) {
        int e = base + (k * ST + t) * 4;
        int4 cc;
        if (e + 3 < E) {
            cc = *reinterpret_cast<const int4*>(col + e);
        } else {
            cc.x = (e     < E) ? col[e]     : -1;
            cc.y = (e + 1 < E) ? col[e + 1] : -1;
            cc.z = (e + 2 < E) ? col[e + 2] : -1;
            cc.w = (e + 3 < E) ? col[e + 3] : -1;
        }
        c[4 * k] = cc.x; c[4 * k + 1] = cc.y; c[4 * k + 2] = cc.z; c[4 * k + 3] = cc.w;
    }
#pragma unroll
    for (int k = 0; k < PT; ++k)
        if (c[k] >= 0) atomicAdd(&loff[((unsigned)c[k] >> CSHIFT) + 1], 1u);
    __syncthreads();

    // ---- wave-0 shuffle scan of loff[0..NC] ----
    if (t < 64) {
        unsigned v[4];
        unsigned ls = 0;
#pragma unroll
        for (int k = 0; k < 4; ++k) {
            int idx = t * 4 + k;
            v[k] = (idx <= NC) ? loff[idx] : 0;
            ls += v[k];
        }
        unsigned sc = ls;
#pragma unroll
        for (int d = 1; d < 64; d <<= 1) {
            unsigned n = __shfl_up(sc, d, 64);
            if (t >= d) sc += n;
        }
        unsigned run = sc - ls;   // exclusive offset for this lane's 4 entries
#pragma unroll
        for (int k = 0; k < 4; ++k) {
            int idx = t * 4 + k;
            run += v[k];
            if (idx <= NC) loff[idx] = run;   // inclusive scan result
        }
    }
    __syncthreads();

    // ---- per-bucket contiguous reservation ----
    if (t < NC) {
        unsigned cb = loff[t + 1] - loff[t];
        gbase[t] = atomicAdd(&gcur[t], cb);
        cur[t] = loff[t];
    }
    __syncthreads();

    // ---- place packed edges into LDS staging (bucket-grouped) ----
#pragma unroll
    for (int k = 0; k < PT / 4; ++k) {
        int e = base + (k * ST + t) * 4;
        int4 rr = make_int4(0, 0, 0, 0);
        if (e + 3 < E) {
            rr = *reinterpret_cast<const int4*>(row + e);
        } else {
            rr.x = (e     < E) ? row[e]     : 0;
            rr.y = (e + 1 < E) ? row[e + 1] : 0;
            rr.z = (e + 2 < E) ? row[e + 2] : 0;
            rr.w = (e + 3 < E) ? row[e + 3] : 0;
        }
        int rl[4] = {rr.x, rr.y, rr.z, rr.w};
#pragma unroll
        for (int j = 0; j < 4; ++j) {
            int cc = c[4 * k + j];
            if (cc >= 0) {
                unsigned b = (unsigned)cc >> CSHIFT;
                unsigned p = atomicAdd(&cur[b], 1u);
                staging[p] = ((unsigned)rl[j] << CSHIFT) | ((unsigned)cc & CMASK);
            }
        }
    }
    __syncthreads();

    // ---- coalesced copy-out: one wave per bucket ----
    const int wave = t >> 6;
    const int lane = t & 63;
    for (int b = wave; b < NC; b += ST / 64) {
        unsigned lo = loff[b];
        unsigned hi = loff[b + 1];
        unsigned gb = gbase[b];
        for (unsigned i = lo + lane; i < hi; i += 64) {
            unsigned off = gb + (i - lo);
            if (off < CAP)                      // 29-sigma overflow guard
                pack1[(unsigned)b * CAP + off] = staging[i];
        }
    }
}

// ==================== stage 2: per-bucket row-tile sub-sort + degree + dinv/xs ====================
// Re-sorts each bucket's entries by row-tile (row>>10) so stage-3 gathers are
// tile-local. Degree counting folds into the scatter loop (replaces k_degk).
// boff[b*(NC+1)+s] = start offset (bucket-relative) of tile s; [..+NC] = cnt.

__global__ __launch_bounds__(CW) void k_subk(unsigned* __restrict__ pack1,
                                             const unsigned* __restrict__ gcur,
                                             const float* __restrict__ x,
                                             float* __restrict__ dinv,
                                             float* __restrict__ xs,
                                             unsigned* __restrict__ boff,
                                             int N, int NC) {
    extern __shared__ unsigned sstage[];   // CAP entries = 96 KB
    __shared__ unsigned loff[NCMAX + 2];
    __shared__ unsigned cur[NCMAX + 1];
    __shared__ unsigned dcnt[CW];
    const int b = blockIdx.x;
    const int t = threadIdx.x;
    dcnt[t] = 0;
    for (int i = t; i <= NC; i += CW) loff[i] = 0;
    __syncthreads();

    const unsigned s0 = (unsigned)b * CAP;
    const unsigned cnt = min(gcur[b], (unsigned)CAP);

    // pass A: histogram row-tiles (tile = p >> 20)
    for (unsigned i = t; i < cnt; i += CW)
        atomicAdd(&loff[(pack1[s0 + i] >> (CSHIFT + 10)) + 1], 1u);
    __syncthreads();

    // wave-0 shuffle scan of loff[0..NC]
    if (t < 64) {
        unsigned v[4];
        unsigned ls = 0;
#pragma unroll
        for (int k = 0; k < 4; ++k) {
            int idx = t * 4 + k;
            v[k] = (idx <= NC) ? loff[idx] : 0;
            ls += v[k];
        }
        unsigned sc = ls;
#pragma unroll
        for (int d = 1; d < 64; d <<= 1) {
            unsigned n = __shfl_up(sc, d, 64);
            if (t >= d) sc += n;
        }
        unsigned run = sc - ls;
#pragma unroll
        for (int k = 0; k < 4; ++k) {
            int idx = t * 4 + k;
            run += v[k];
            if (idx <= NC) loff[idx] = run;
        }
    }
    __syncthreads();
    if (t <= NC) boff[(size_t)b * (NC + 1) + t] = loff[t];
    if (t < NC) cur[t] = loff[t];
    __syncthreads();

    // pass B: scatter into LDS staging by tile; fold degree count
    for (unsigned i = t; i < cnt; i += CW) {
        unsigned p = pack1[s0 + i];
        unsigned tile = p >> (CSHIFT + 10);
        unsigned pos = atomicAdd(&cur[tile], 1u);
        sstage[pos] = p;
        atomicAdd(&dcnt[p & CMASK], 1u);
    }
    __syncthreads();

    // write back reordered bucket (coalesced) + node-wise dinv/xs
    for (unsigned i = t; i < cnt; i += CW)
        pack1[s0 + i] = sstage[i];
    int v = (b << CSHIFT) + t;
    if (v < N) {
        float di = rsqrtf((float)dcnt[t] + 1.0f);
        dinv[v] = di;
        xs[v] = di * x[v];
    }
}

// ==================== stage 3: tile-staged gather kernels ====================
// Per-wave row tile: wave loads 4 KB of xs/gs into its private LDS tile
// (coalesced), then that tile's edges gather from LDS. No per-tile barrier.

__global__ __launch_bounds__(CW) void k_l1k(const unsigned* __restrict__ pack1,
                                            const unsigned* __restrict__ boff,
                                            const float* __restrict__ xs,
                                            const float* __restrict__ dinv,
                                            const float* __restrict__ W1,
                                            const float* __restrict__ b1,
                                            const float* __restrict__ W2,
                                            float* __restrict__ gs, int N, int NC) {
    extern __shared__ float xtile[];       // NWAVE * 1024 floats = 64 KB
    __shared__ float acc[CW];
    __shared__ unsigned bo[NCMAX + 2];
    const int b = blockIdx.x;
    const int t = threadIdx.x;
    const int w = t >> 6;
    const int lane = t & 63;
    acc[t] = 0.0f;
    if (t <= NC) bo[t] = boff[(size_t)b * (NC + 1) + t];
    __syncthreads();

    const unsigned s0 = (unsigned)b * CAP;
    const int n44 = N >> 2;
    const float4* x4 = reinterpret_cast<const float4*>(xs);
    float4* tile4 = reinterpret_cast<float4*>(xtile + (w << 10));

    for (int s = w; s < NC; s += NWAVE) {
        unsigned off0 = bo[s];
        unsigned off1 = bo[s + 1];
        if (off0 == off1) continue;
        int base4 = s << 8;
#pragma unroll
        for (int k = 0; k < 4; ++k) {
            int q = lane + (k << 6);
            int idx = base4 + q;
            tile4[q] = (idx < n44) ? x4[idx] : make_float4(0.f, 0.f, 0.f, 0.f);
        }
        asm volatile("s_waitcnt lgkmcnt(0) vmcnt(0)" ::: "memory");
        for (unsigned i = off0 + lane; i < off1; i += 64) {
            unsigned p = pack1[s0 + i];
            float val = xtile[(w << 10) | ((p >> CSHIFT) & CMASK)];
            atomicAdd(&acc[p & CMASK], val);
        }
    }
    __syncthreads();
    int v = (b << CSHIFT) + t;
    if (v < N) {
        float di = dinv[v];
        float tt = di * (acc[t] + xs[v]);  // + self-loop
        float g = 0.0f;
#pragma unroll
        for (int jj = 0; jj < 16; ++jj) {
            float y = fmaxf(fmaf(W1[jj], tt, b1[jj]), 0.0f);
            g = fmaf(W2[2 * jj] - W2[2 * jj + 1], y, g);
        }
        gs[v] = di * g;
    }
}

__global__ __launch_bounds__(CW) void k_l2k(const unsigned* __restrict__ pack1,
                                            const unsigned* __restrict__ boff,
                                            const float* __restrict__ gs,
                                            const float* __restrict__ dinv,
                                            const float* __restrict__ b2,
                                            float* __restrict__ out, int N, int NC) {
    extern __shared__ float xtile[];
    __shared__ float acc[CW];
    __shared__ unsigned bo[NCMAX + 2];
    const int b = blockIdx.x;
    const int t = threadIdx.x;
    const int w = t >> 6;
    const int lane = t & 63;
    acc[t] = 0.0f;
    if (t <= NC) bo[t] = boff[(size_t)b * (NC + 1) + t];
    __syncthreads();

    const unsigned s0 = (unsigned)b * CAP;
    const int n44 = N >> 2;
    const float4* g4 = reinterpret_cast<const float4*>(gs);
    float4* tile4 = reinterpret_cast<float4*>(xtile + (w << 10));

    for (int s = w; s < NC; s += NWAVE) {
        unsigned off0 = bo[s];
        unsigned off1 = bo[s + 1];
        if (off0 == off1) continue;
        int base4 = s << 8;
#pragma unroll
        for (int k = 0; k < 4; ++k) {
            int q = lane + (k << 6);
            int idx = base4 + q;
            tile4[q] = (idx < n44) ? g4[idx] : make_float4(0.f, 0.f, 0.f, 0.f);
        }
        asm volatile("s_waitcnt lgkmcnt(0) vmcnt(0)" ::: "memory");
        for (unsigned i = off0 + lane; i < off1; i += 64) {
            unsigned p = pack1[s0 + i];
            float val = xtile[(w << 10) | ((p >> CSHIFT) & CMASK)];
            atomicAdd(&acc[p & CMASK], val);
        }
    }
    __syncthreads();
    int v = (b << CSHIFT) + t;
    if (v < N) {
        float diff = dinv[v] * (acc[t] + gs[v]) + (b2[0] - b2[1]);
        float p0 = 1.0f / (1.0f + __expf(-diff));
        float2 o;
        o.x = p0;
        o.y = 1.0f - p0;
        reinterpret_cast<float2*>(out)[v] = o;
    }
}

// ==================== generic fallback (R2 atomic path, any sizes) ====================
__global__ void k_zero_f(float* __restrict__ p, int n) {
    int i = blockIdx.x * blockDim.x + threadIdx.x;
    int v = i * 4;
    if (v + 3 < n) {
        reinterpret_cast<float4*>(p + v)[0] = make_float4(0.f, 0.f, 0.f, 0.f);
    } else {
        for (; v < n; ++v) p[v] = 0.0f;
    }
}
__global__ void k_deg_f(const int* __restrict__ col, float* __restrict__ deg, int E) {
    int i = blockIdx.x * blockDim.x + threadIdx.x;
    int e = i * 4;
    if (e + 3 < E) {
        int4 c = reinterpret_cast<const int4*>(col + e)[0];
        atomicAdd(deg + c.x, 1.0f); atomicAdd(deg + c.y, 1.0f);
        atomicAdd(deg + c.z, 1.0f); atomicAdd(deg + c.w, 1.0f);
    } else {
        for (; e < E; ++e) atomicAdd(deg + col[e], 1.0f);
    }
}
__global__ void k_node1_f(const float* __restrict__ x, float* __restrict__ degdinv,
                          float* __restrict__ xs, int N) {
    int v = blockIdx.x * blockDim.x + threadIdx.x;
    if (v < N) {
        float dinv = rsqrtf(degdinv[v] + 1.0f);
        degdinv[v] = dinv;
        xs[v] = dinv * x[v];
    }
}
__global__ void k_scat_f(const int* __restrict__ row, const int* __restrict__ col,
                         const float* __restrict__ src, float* __restrict__ acc, int E) {
    int i = blockIdx.x * blockDim.x + threadIdx.x;
    int e = i * 4;
    if (e + 3 < E) {
        int4 r = reinterpret_cast<const int4*>(row + e)[0];
        int4 c = reinterpret_cast<const int4*>(col + e)[0];
        float s0 = src[r.x], s1 = src[r.y], s2 = src[r.z], s3 = src[r.w];
        atomicAdd(acc + c.x, s0); atomicAdd(acc + c.y, s1);
        atomicAdd(acc + c.z, s2); atomicAdd(acc + c.w, s3);
    } else {
        for (; e < E; ++e) atomicAdd(acc + col[e], src[row[e]]);
    }
}
__global__ void k_mlp_f(const float* __restrict__ W1, const float* __restrict__ b1,
                        const float* __restrict__ W2, const float* __restrict__ dinv,
                        float* __restrict__ acc, float* __restrict__ xsgs, int N) {
    int v = blockIdx.x * blockDim.x + threadIdx.x;
    if (v < N) {
        float di = dinv[v];
        float t = di * (acc[v] + xsgs[v]);
        float g = 0.0f;
#pragma unroll
        for (int j = 0; j < 16; ++j) {
            float y = fmaxf(fmaf(W1[j], t, b1[j]), 0.0f);
            g = fmaf(W2[2 * j] - W2[2 * j + 1], y, g);
        }
        xsgs[v] = di * g;
        acc[v] = 0.0f;
    }
}
__global__ void k_out_f(const float* __restrict__ b2, const float* __restrict__ dinv,
                        const float* __restrict__ acc, const float* __restrict__ gs,
                        float* __restrict__ out, int N) {
    int v = blockIdx.x * blockDim.x + threadIdx.x;
    if (v < N) {
        float diff = dinv[v] * (acc[v] + gs[v]) + (b2[0] - b2[1]);
        float p0 = 1.0f / (1.0f + __expf(-diff));
        float2 o; o.x = p0; o.y = 1.0f - p0;
        reinterpret_cast<float2*>(out)[v] = o;
    }
}

extern "C" void kernel_launch(void* const* d_in, const int* in_sizes, int n_in,
                              void* d_out, int out_size, void* d_ws, size_t ws_size,
                              hipStream_t stream) {
    const float* x  = (const float*)d_in[0];
    const int* edge = (const int*)d_in[1];   // int64 in reference -> int32 in harness
    const float* W1 = (const float*)d_in[2];
    const float* b1 = (const float*)d_in[3];
    const float* W2 = (const float*)d_in[4];
    const float* b2 = (const float*)d_in[5];
    float* out = (float*)d_out;

    const int N = in_sizes[0];
    const int E = in_sizes[1] / 2;
    const int* row = edge;       // sources
    const int* col = edge + E;   // targets

    const int NC  = (N + CW - 1) >> CSHIFT;            // buckets == row tiles (245)
    const int NBS = (E + EPB - 1) / EPB;               // sort blocks (489)

    // Capacity check: mean + 8 sigma must fit CAP.
    const double mean = (double)E / NC;
    const double slack = mean + 8.0 * __builtin_sqrt(mean > 1.0 ? mean : 1.0);
    // ws: pack1[NC*CAP] | gcur[NC] | boff[NC*(NC+1)] (u32) then dinv|xs|gs (floats)
    const size_t need = ((size_t)NC * CAP + NC + (size_t)NC * (NC + 1)) * 4 +
                        (size_t)3 * N * 4;

    if (NC <= NCMAX && N < (1 << 22) && (N & 3) == 0 && slack < CAP &&
        ws_size >= need) {
        unsigned* pack1 = (unsigned*)d_ws;
        unsigned* gcur  = pack1 + (size_t)NC * CAP;
        unsigned* boff  = gcur + NC;
        float* dinv     = (float*)(boff + (size_t)NC * (NC + 1));
        float* xs       = dinv + N;
        float* gs       = xs + N;

        // dynamic LDS > 64 KB default: raise caps once (host-side, capture-safe).
        static bool attr_done = false;
        if (!attr_done) {
            hipFuncSetAttribute((const void*)k_subk,
                                hipFuncAttributeMaxDynamicSharedMemorySize, CAP * 4);
            hipFuncSetAttribute((const void*)k_l1k,
                                hipFuncAttributeMaxDynamicSharedMemorySize,
                                NWAVE * 1024 * 4);
            hipFuncSetAttribute((const void*)k_l2k,
                                hipFuncAttributeMaxDynamicSharedMemorySize,
                                NWAVE * 1024 * 4);
            attr_done = true;
        }

        // Split launches: kernel boundary is the cheap device-wide sync on
        // gfx950 (cooperative grid.sync -> 3.5x regression, R8).
        hipMemsetAsync(gcur, 0, (size_t)NC * sizeof(unsigned), stream);
        k_sortk<<<NBS, ST, 0, stream>>>(row, col, gcur, pack1, E, NC);
        k_subk <<<NC, CW, CAP * 4, stream>>>(pack1, gcur, x, dinv, xs, boff, N, NC);
        k_l1k  <<<NC, CW, NWAVE * 1024 * 4, stream>>>(pack1, boff, xs, dinv, W1, b1,
                                                      W2, gs, N, NC);
        k_l2k  <<<NC, CW, NWAVE * 1024 * 4, stream>>>(pack1, boff, gs, dinv, b2, out,
                                                      N, NC);
    } else {
        // generic fallback: R2 atomic-scatter path
        float* w0 = (float*)d_ws;
        float* w1 = w0 + N;
        float* w2 = w1 + N;
        const int nb = (N + 255) / 256;
        const int eb = ((E + 3) / 4 + 255) / 256;
        const int zb = ((2 * N + 3) / 4 + 255) / 256;
        k_zero_f <<<zb, 256, 0, stream>>>(w0, 2 * N);
        k_deg_f  <<<eb, 256, 0, stream>>>(col, w0, E);
        k_node1_f<<<nb, 256, 0, stream>>>(x, w0, w2, N);
        k_scat_f <<<eb, 256, 0, stream>>>(row, col, w2, w1, E);
        k_mlp_f  <<<nb, 256, 0, stream>>>(W1, b1, W2, w0, w1, w2, N);
        k_scat_f <<<eb, 256, 0, stream>>>(row, col, w2, w1, E);
        k_out_f  <<<nb, 256, 0, stream>>>(b2, w0, w1, w2, out, N);
    }
}